// Round 9
// baseline (361.211 us; speedup 1.0000x reference)
//
#include <hip/hip_runtime.h>

#define N_NODES 100000
#define N_TYPES 7
#define N_EDGES 400000
#define DIM 128
#define NTOT (N_TYPES * N_NODES)   // 700000
#define ETOT (N_TYPES * N_EDGES)   // 2800000

// bucketed CSR build
#define RBITS 10
#define RNODE 1024
#define NBUCK 98                   // ceil(N_NODES / RNODE)
#define BSTRIDE 128                // padded bucket stride per type
#define CAP 6144                   // per-bucket capacity (mean 4096, +32 sigma)
#define CHUNK 2048
#define NCHUNKS ((N_EDGES + CHUNK - 1) / CHUNK)   // 196

typedef short v8s __attribute__((ext_vector_type(8)));   // 8 bf16 (4 VGPRs)
typedef float v4f __attribute__((ext_vector_type(4)));   // 4 f32 acc

__device__ __forceinline__ unsigned short f2bf(float f) {
    unsigned int x = __float_as_uint(f);
    return (unsigned short)((x + 0x7FFFu + ((x >> 16) & 1u)) >> 16);   // RNE
}

// ---------------------------------------------------------------------------
// casts
// ---------------------------------------------------------------------------
__global__ __launch_bounds__(256) void cast_x_kernel(
    const float* __restrict__ x, unsigned short* __restrict__ xb)
{
    int i = blockIdx.x * 256 + threadIdx.x;            // one float4 each
    if (i >= N_NODES * DIM / 4) return;
    float4 v = reinterpret_cast<const float4*>(x)[i];
    ushort4 o;
    o.x = f2bf(v.x); o.y = f2bf(v.y); o.z = f2bf(v.z); o.w = f2bf(v.w);
    reinterpret_cast<ushort4*>(xb)[i] = o;
}

// WT[t][j][k] = bf16(W[t][k][j])
__global__ __launch_bounds__(256) void cast_wt_kernel(
    const float* __restrict__ W, unsigned short* __restrict__ WT)
{
    int i = blockIdx.x * 256 + threadIdx.x;
    if (i >= N_TYPES * DIM * DIM) return;
    int t = i >> 14, r = i & 16383, j = r >> 7, k = r & 127;
    WT[i] = f2bf(W[(t << 14) + (k << 7) + j]);
}

__global__ __launch_bounds__(128) void bsum_kernel(
    const float* __restrict__ b, float* __restrict__ bsum)
{
    int j = threadIdx.x;
    float s = 0.f;
    for (int t = 0; t < N_TYPES; ++t) s += b[t * DIM + j];
    bsum[j] = s;
}

// ---------------------------------------------------------------------------
// binpass: LDS-sort each 2048-edge chunk by bucket (dst>>10), write each
// bucket's run contiguously. Entry = (dst&1023)<<17 | src.
// ---------------------------------------------------------------------------
__global__ __launch_bounds__(256) void binpass_kernel(
    const int* __restrict__ ei, int* __restrict__ gcur,
    unsigned int* __restrict__ bucketbuf)
{
    __shared__ unsigned int packedLds[CHUNK];
    __shared__ unsigned char bLds[CHUNK];
    __shared__ unsigned int sortedLds[CHUNK];
    __shared__ int cnt[BSTRIDE];
    __shared__ int lofs[BSTRIDE];
    __shared__ int gbase[BSTRIDE];

    const int blk = blockIdx.x;
    const int t = blk / NCHUNKS;
    const int c = blk - t * NCHUNKS;
    const int* srcp = ei + (size_t)t * 2 * N_EDGES;
    const int* dstp = srcp + N_EDGES;
    const int e0 = c * CHUNK;
    const int e1 = min(e0 + CHUNK, N_EDGES);
    const int tid = threadIdx.x;

    if (tid < BSTRIDE) cnt[tid] = 0;
    __syncthreads();

#pragma unroll
    for (int k = 0; k < CHUNK / 256; ++k) {
        int j = tid + k * 256;
        int e = e0 + j;
        unsigned char b = 0xFF;
        unsigned int pk = 0;
        if (e < e1) {
            int s = srcp[e];
            int d = dstp[e];
            b = (unsigned char)(d >> RBITS);
            pk = ((unsigned int)(d & (RNODE - 1)) << 17) | (unsigned int)s;
            atomicAdd(&cnt[b], 1);
        }
        packedLds[j] = pk;
        bLds[j] = b;
    }
    __syncthreads();

    if (tid < BSTRIDE) lofs[tid] = cnt[tid];
    __syncthreads();
    for (int off = 1; off < BSTRIDE; off <<= 1) {
        int tv = 0;
        if (tid >= off && tid < BSTRIDE) tv = lofs[tid - off];
        __syncthreads();
        if (tid < BSTRIDE) lofs[tid] += tv;
        __syncthreads();
    }
    if (tid < BSTRIDE) lofs[tid] -= cnt[tid];
    __syncthreads();

    if (tid < BSTRIDE) {
        int n = cnt[tid];
        int base = -1;
        if (n > 0 && tid < NBUCK) {
            int rel = atomicAdd(&gcur[t * BSTRIDE + tid], n);
            base = (t * BSTRIDE + tid) * CAP + rel;
        }
        gbase[tid] = base;
        cnt[tid] = lofs[tid];
    }
    __syncthreads();

#pragma unroll
    for (int k = 0; k < CHUNK / 256; ++k) {
        int j = tid + k * 256;
        unsigned char b = bLds[j];
        if (b != 0xFF) {
            int p = atomicAdd(&cnt[b], 1);
            sortedLds[p] = packedLds[j];
        }
    }
    __syncthreads();

    const int wave = tid >> 6, lane = tid & 63;
    for (int b = wave * 32; b < wave * 32 + 32; ++b) {
        if (b >= NBUCK) break;
        int base = gbase[b];
        if (base < 0) continue;
        int o = lofs[b];
        int n = cnt[b] - o;
        for (int i = lane; i < n; i += 64)
            bucketbuf[(size_t)base + i] = sortedLds[o + i];
    }
}

// ---------------------------------------------------------------------------
// bucket_hist: per (type,bucket), count node degrees in LDS, write deg.
// ---------------------------------------------------------------------------
__global__ __launch_bounds__(256) void bucket_hist_kernel(
    const unsigned int* __restrict__ bucketbuf, const int* __restrict__ gcur,
    int* __restrict__ deg)
{
    __shared__ int cnt[RNODE];
    const int blk = blockIdx.x;
    const int t = blk / NBUCK;
    const int b = blk - t * NBUCK;
    const int n = min(gcur[t * BSTRIDE + b], CAP);
    const int g0 = b << RBITS;
    const int validR = min(RNODE, N_NODES - g0);
    const int tid = threadIdx.x;
    for (int j = tid; j < RNODE; j += 256) cnt[j] = 0;
    __syncthreads();
    const unsigned int* bb = bucketbuf + (size_t)(t * BSTRIDE + b) * CAP;
    for (int i = tid; i < n; i += 256)
        atomicAdd(&cnt[bb[i] >> 17], 1);
    __syncthreads();
    int* dg = deg + (size_t)t * N_NODES + g0;
    for (int j = tid; j < validR; j += 256) dg[j] = cnt[j];
}

// ---------------------------------------------------------------------------
// global exclusive scan of deg -> offs
// ---------------------------------------------------------------------------
__global__ __launch_bounds__(256) void scan1_kernel(
    const int* __restrict__ deg, int* __restrict__ offs, int* __restrict__ bsum)
{
    __shared__ int s[256];
    int tid = threadIdx.x;
    int base = blockIdx.x * 1024 + tid * 4;
    int v[4];
    int tot = 0;
#pragma unroll
    for (int j = 0; j < 4; ++j) {
        v[j] = (base + j < NTOT) ? deg[base + j] : 0;
        tot += v[j];
    }
    s[tid] = tot;
    __syncthreads();
    for (int off = 1; off < 256; off <<= 1) {
        int t2 = (tid >= off) ? s[tid - off] : 0;
        __syncthreads();
        s[tid] += t2;
        __syncthreads();
    }
    if (tid == 255) bsum[blockIdx.x] = s[255];
    int run = s[tid] - tot;
#pragma unroll
    for (int j = 0; j < 4; ++j) {
        if (base + j < NTOT) offs[base + j] = run;
        run += v[j];
    }
}

__global__ __launch_bounds__(1024) void scan2_kernel(int* __restrict__ bsum, int nb)
{
    __shared__ int s[1024];
    int tid = threadIdx.x;
    int v = (tid < nb) ? bsum[tid] : 0;
    s[tid] = v;
    __syncthreads();
    for (int off = 1; off < 1024; off <<= 1) {
        int t2 = (tid >= off) ? s[tid - off] : 0;
        __syncthreads();
        s[tid] += t2;
        __syncthreads();
    }
    if (tid < nb) bsum[tid] = s[tid] - v;
}

__global__ __launch_bounds__(256) void scan3_kernel(
    int* __restrict__ offs, const int* __restrict__ bsum)
{
    int i = blockIdx.x * 256 + threadIdx.x;
    if (i < NTOT) offs[i] += bsum[i >> 10];
    if (i == 0) offs[NTOT] = ETOT;
}

// ---------------------------------------------------------------------------
// place: per (type,bucket), counting-sort into the contiguous CSR segment.
// ---------------------------------------------------------------------------
__global__ __launch_bounds__(256) void place_kernel(
    const unsigned int* __restrict__ bucketbuf, const int* __restrict__ gcur,
    const int* __restrict__ offs, int* __restrict__ srcperm)
{
    __shared__ int cur[RNODE];
    __shared__ int sorted[CAP];
    const int blk = blockIdx.x;
    const int t = blk / NBUCK;
    const int b = blk - t * NBUCK;
    const int n = min(gcur[t * BSTRIDE + b], CAP);
    const int g0 = b << RBITS;
    const int validR = min(RNODE, N_NODES - g0);
    const int tid = threadIdx.x;
    const int* offt = offs + (size_t)t * N_NODES + g0;
    const int base0 = offt[0];
    for (int j = tid; j < validR; j += 256) cur[j] = offt[j] - base0;
    __syncthreads();
    const unsigned int* bb = bucketbuf + (size_t)(t * BSTRIDE + b) * CAP;
    for (int i = tid; i < n; i += 256) {
        unsigned int pk = bb[i];
        int p = atomicAdd(&cur[pk >> 17], 1);
        sorted[p] = (int)(pk & 0x1FFFFu);
    }
    __syncthreads();
    int* outp = srcperm + base0;
    for (int i = tid; i < n; i += 256) outp[i] = sorted[i];
}

// ---------------------------------------------------------------------------
// Fused aggregate + MFMA, barrier-free.
// Block: 256 thr = 4 waves, 64 rows. Wave owns 16 rows; its 4 16-lane groups
// each aggregate 4 rows CONCURRENTLY (4 gathers in flight/lane, predicated on
// the 4-row max degree) into wave-private XOR-swizzled LDS (4 KB/wave).
// B-fragments load straight from global WT (L2-hot, 16x64B lines per load).
// acc carries across all 7 types; single f32 out write.
// ---------------------------------------------------------------------------
__global__ __launch_bounds__(256, 4) void fused_kernel(
    const unsigned short* __restrict__ xb,
    const int* __restrict__ offs,
    const int* __restrict__ srcperm,
    const unsigned short* __restrict__ WT,
    const float* __restrict__ bsum,
    float* __restrict__ out)
{
    __shared__ unsigned short sA[4][16 * DIM];   // 16 KB total, wave-private 4KB

    const int tid = threadIdx.x;
    const int wave = tid >> 6;
    const int lane = tid & 63;
    const int l = lane & 15;            // lane in 16-lane group
    const int gw = lane >> 4;           // group in wave (0..3)
    const int khi = lane >> 4;          // MFMA k-chunk (same bits, diff use)
    const int rlo = lane & 15;
    const int row0 = blockIdx.x * 64;
    const int wrow0 = row0 + wave * 16;
    unsigned short* myA = sA[wave];

    v4f acc[8];
#pragma unroll
    for (int n = 0; n < 8; ++n) acc[n] = (v4f){0.f, 0.f, 0.f, 0.f};

    for (int t = 0; t < N_TYPES; ++t) {
        // ---- aggregate this group's 4 rows concurrently ----
        int begs[4], ms[4];
#pragma unroll
        for (int i = 0; i < 4; ++i) {
            int g = wrow0 + gw * 4 + i;
            bool vld = g < N_NODES;
            int grp = t * N_NODES + (vld ? g : 0);
            int b0 = offs[grp];
            int e0 = offs[grp + 1];
            begs[i] = b0;
            ms[i] = vld ? (e0 - b0) : 0;
        }
        int mm = max(max(ms[0], ms[1]), max(ms[2], ms[3]));

        float a[4][8];
#pragma unroll
        for (int i = 0; i < 4; ++i)
#pragma unroll
            for (int j = 0; j < 8; ++j) a[i][j] = 0.f;

        for (int it = 0; it < mm; ++it) {
            uint4 v[4];
            float w[4];
#pragma unroll
            for (int i = 0; i < 4; ++i) {
                bool valid = it < ms[i];
                int e = valid ? (begs[i] + it) : 0;
                int s = srcperm[e];
                v[i] = *reinterpret_cast<const uint4*>(
                    reinterpret_cast<const char*>(xb) + ((size_t)s << 8) + (l << 4));
                w[i] = valid ? 1.f : 0.f;
            }
#pragma unroll
            for (int i = 0; i < 4; ++i) {
                a[i][0] += w[i] * __uint_as_float(v[i].x << 16);
                a[i][1] += w[i] * __uint_as_float(v[i].x & 0xFFFF0000u);
                a[i][2] += w[i] * __uint_as_float(v[i].y << 16);
                a[i][3] += w[i] * __uint_as_float(v[i].y & 0xFFFF0000u);
                a[i][4] += w[i] * __uint_as_float(v[i].z << 16);
                a[i][5] += w[i] * __uint_as_float(v[i].z & 0xFFFF0000u);
                a[i][6] += w[i] * __uint_as_float(v[i].w << 16);
                a[i][7] += w[i] * __uint_as_float(v[i].w & 0xFFFF0000u);
            }
        }

        // ---- pack means into wave-private swizzled LDS ----
#pragma unroll
        for (int i = 0; i < 4; ++i) {
            float inv = 1.0f / fmaxf((float)ms[i], 1.0f);
            unsigned int p0, p1, p2, p3;
            asm("v_cvt_pk_bf16_f32 %0, %1, %2" : "=v"(p0) : "v"(a[i][0] * inv), "v"(a[i][1] * inv));
            asm("v_cvt_pk_bf16_f32 %0, %1, %2" : "=v"(p1) : "v"(a[i][2] * inv), "v"(a[i][3] * inv));
            asm("v_cvt_pk_bf16_f32 %0, %1, %2" : "=v"(p2) : "v"(a[i][4] * inv), "v"(a[i][5] * inv));
            asm("v_cvt_pk_bf16_f32 %0, %1, %2" : "=v"(p3) : "v"(a[i][6] * inv), "v"(a[i][7] * inv));
            uint4 o = make_uint4(p0, p1, p2, p3);
            int r = gw * 4 + i;
            int byte = (r << 8) + ((l << 4) ^ ((r & 7) << 4));
            *reinterpret_cast<uint4*>(reinterpret_cast<char*>(myA) + byte) = o;
        }
        // same-wave ds_write -> ds_read: compiler inserts lgkmcnt; no barrier.

        // ---- MFMA: A from wave LDS, B straight from global (L2-hot) ----
        const unsigned short* wt = WT + ((size_t)t << 14);
#pragma unroll
        for (int k0 = 0; k0 < DIM; k0 += 32) {
            int colb = (k0 << 1) + (khi << 4);
            int abyte = (rlo << 8) + (colb ^ ((rlo & 7) << 4));
            v8s afr = *reinterpret_cast<const v8s*>(
                reinterpret_cast<const char*>(myA) + abyte);
#pragma unroll
            for (int n = 0; n < 8; ++n) {
                int col = (n << 4) | rlo;
                v8s bfr = *reinterpret_cast<const v8s*>(
                    wt + (col << 7) + k0 + (khi << 3));
                acc[n] = __builtin_amdgcn_mfma_f32_16x16x32_bf16(afr, bfr, acc[n], 0, 0, 0);
            }
        }
    }

    // ---- epilogue: out = (acc + bsum) / 7 ----
    const float inv7 = 1.0f / 7.0f;
#pragma unroll
    for (int n = 0; n < 8; ++n) {
        int col = (n << 4) | rlo;
        float bs = bsum[col];
#pragma unroll
        for (int r = 0; r < 4; ++r) {
            int row = wrow0 + (khi << 2) + r;
            if (row < N_NODES)
                out[((size_t)row << 7) + col] = (acc[n][r] + bs) * inv7;
        }
    }
}

extern "C" void kernel_launch(void* const* d_in, const int* in_sizes, int n_in,
                              void* d_out, int out_size, void* d_ws, size_t ws_size,
                              hipStream_t stream) {
    const float* x  = (const float*)d_in[0];
    const int*   ei = (const int*)d_in[1];     // [N_TYPES, 2, N_EDGES] int32
    const float* W  = (const float*)d_in[2];
    const float* b  = (const float*)d_in[3];
    float* out = (float*)d_out;

    // ---- workspace layout ----
    char* p = (char*)d_ws;
    unsigned short* xb = (unsigned short*)p;          p += (size_t)N_NODES * DIM * 2;       // 25.6 MB
    unsigned short* WT = (unsigned short*)p;          p += (size_t)N_TYPES * DIM * DIM * 2; // 229 KB
    float* bsum = (float*)p;                          p += 512;
    int* srcperm = (int*)p;                           p += (size_t)ETOT * 4;                // 11.2 MB
    int* deg = (int*)p;                               p += (size_t)NTOT * 4;                // 2.8 MB
    int* offs = (int*)p;                              p += (size_t)(NTOT + 1) * 4;          // 2.8 MB
    int* bscan = (int*)p;                             p += 1024 * 4;
    int* gcur = (int*)p;                              p += (size_t)N_TYPES * BSTRIDE * 4;
    p = (char*)(((uintptr_t)p + 15) & ~(uintptr_t)15);
    unsigned int* bucketbuf = (unsigned int*)p;       // 7*128*6144*4 = 22 MB

    const int NB = (NTOT + 1023) / 1024;              // 684

    cast_x_kernel<<<(N_NODES * DIM / 4 + 255) / 256, 256, 0, stream>>>(x, xb);
    cast_wt_kernel<<<(N_TYPES * DIM * DIM + 255) / 256, 256, 0, stream>>>(W, WT);
    bsum_kernel<<<1, 128, 0, stream>>>(b, bsum);

    hipMemsetAsync(gcur, 0, (size_t)N_TYPES * BSTRIDE * 4, stream);
    binpass_kernel<<<N_TYPES * NCHUNKS, 256, 0, stream>>>(ei, gcur, bucketbuf);
    bucket_hist_kernel<<<N_TYPES * NBUCK, 256, 0, stream>>>(bucketbuf, gcur, deg);
    scan1_kernel<<<NB, 256, 0, stream>>>(deg, offs, bscan);
    scan2_kernel<<<1, 1024, 0, stream>>>(bscan, NB);
    scan3_kernel<<<(NTOT + 255) / 256, 256, 0, stream>>>(offs, bscan);
    place_kernel<<<N_TYPES * NBUCK, 256, 0, stream>>>(bucketbuf, gcur, offs, srcperm);

    const int fused_blocks = (N_NODES + 63) / 64;     // 1563
    fused_kernel<<<fused_blocks, 256, 0, stream>>>(xb, offs, srcperm, WT, bsum, out);
}